// Round 1
// baseline (605.456 us; speedup 1.0000x reference)
//
#include <hip/hip_runtime.h>

#define NN 40000
#define NE 640000
#define F 128
#define NG 64

// ---------------- degree histogram ----------------
__global__ __launch_bounds__(256) void k_deg(const int* __restrict__ col, int* __restrict__ deg) {
    int e = blockIdx.x * 256 + threadIdx.x;
    if (e < NE) atomicAdd(&deg[col[e]], 1);
}

__global__ __launch_bounds__(256) void k_dinv(const int* __restrict__ deg, float* __restrict__ dinv) {
    int v = blockIdx.x * 256 + threadIdx.x;
    if (v < NN) dinv[v] = rsqrtf((float)(deg[v] + 1));  // +1 self-loop
}

// ---------------- exclusive scan (single block) ----------------
__global__ __launch_bounds__(1024) void k_scan(const int* __restrict__ deg, int* __restrict__ indptr,
                                               int* __restrict__ cursor) {
    __shared__ int part[1024];
    int t = threadIdx.x;
    const int CH = 40;  // 1024*40 >= 40000
    int base = t * CH;
    int s = 0;
    for (int i = 0; i < CH; i++) {
        int idx = base + i;
        if (idx < NN) s += deg[idx];
    }
    part[t] = s;
    __syncthreads();
    for (int off = 1; off < 1024; off <<= 1) {
        int add = (t >= off) ? part[t - off] : 0;
        __syncthreads();
        part[t] += add;
        __syncthreads();
    }
    int run = (t == 0) ? 0 : part[t - 1];
    for (int i = 0; i < CH; i++) {
        int idx = base + i;
        if (idx < NN) {
            indptr[idx] = run;
            cursor[idx] = run;
            run += deg[idx];
        }
    }
    if (t == 1023) indptr[NN] = part[1023];
}

// ---------------- CSR fill ----------------
__global__ __launch_bounds__(256) void k_fill(const int* __restrict__ row, const int* __restrict__ col,
                                              int* __restrict__ cursor, int* __restrict__ esrc) {
    int e = blockIdx.x * 256 + threadIdx.x;
    if (e < NE) {
        int c = col[e];
        int slot = atomicAdd(&cursor[c], 1);
        esrc[slot] = row[e];
    }
}

// ---------------- GEMM: B[40000x128] = act(A) @ W[128x128] ----------------
// act = identity (layer1) or BN+ReLU with scale/shift (layer2 input)
template <bool BN>
__global__ __launch_bounds__(256) void k_gemm(const float* __restrict__ A, const float* __restrict__ W,
                                              float* __restrict__ B, const float* __restrict__ scale,
                                              const float* __restrict__ shift) {
    __shared__ float Ws[128 * 128];
    int t = threadIdx.x;
    {
        const float4* W4 = (const float4*)W;
        float4* Ws4 = (float4*)Ws;
#pragma unroll
        for (int i = 0; i < 16; i++) Ws4[t + i * 256] = W4[t + i * 256];
    }
    __syncthreads();
    int r0 = blockIdx.x * 64;
    int cg = t & 31, rg = t >> 5;
    int c0 = cg * 4;
    float acc[8][4];
#pragma unroll
    for (int i = 0; i < 8; i++)
#pragma unroll
        for (int j = 0; j < 4; j++) acc[i][j] = 0.f;

    for (int k = 0; k < 128; k += 4) {
        float4 w0 = *(const float4*)&Ws[(k + 0) * 128 + c0];
        float4 w1 = *(const float4*)&Ws[(k + 1) * 128 + c0];
        float4 w2 = *(const float4*)&Ws[(k + 2) * 128 + c0];
        float4 w3 = *(const float4*)&Ws[(k + 3) * 128 + c0];
        float4 sc4, sh4;
        if (BN) {
            sc4 = *(const float4*)&scale[k];
            sh4 = *(const float4*)&shift[k];
        }
#pragma unroll
        for (int i = 0; i < 8; i++) {
            int r = r0 + rg + i * 8;
            float4 a = *(const float4*)&A[r * 128 + k];
            if (BN) {
                a.x = fmaxf(fmaf(a.x, sc4.x, sh4.x), 0.f);
                a.y = fmaxf(fmaf(a.y, sc4.y, sh4.y), 0.f);
                a.z = fmaxf(fmaf(a.z, sc4.z, sh4.z), 0.f);
                a.w = fmaxf(fmaf(a.w, sc4.w, sh4.w), 0.f);
            }
            acc[i][0] += a.x * w0.x + a.y * w1.x + a.z * w2.x + a.w * w3.x;
            acc[i][1] += a.x * w0.y + a.y * w1.y + a.z * w2.y + a.w * w3.y;
            acc[i][2] += a.x * w0.z + a.y * w1.z + a.z * w2.z + a.w * w3.z;
            acc[i][3] += a.x * w0.w + a.y * w1.w + a.z * w2.w + a.w * w3.w;
        }
    }
#pragma unroll
    for (int i = 0; i < 8; i++) {
        int r = r0 + rg + i * 8;
        *(float4*)&B[r * 128 + c0] = make_float4(acc[i][0], acc[i][1], acc[i][2], acc[i][3]);
    }
}

// ---------------- aggregation: out[v] = (sum_in h[r]*dinv[r] + h[v]*dinv[v])*dinv[v] + b ----------------
__global__ __launch_bounds__(256) void k_agg(const float* __restrict__ hin, const int* __restrict__ indptr,
                                             const int* __restrict__ esrc, const float* __restrict__ dinv,
                                             const float* __restrict__ bias, float* __restrict__ hout) {
    __shared__ float buf[128];
    int t = threadIdx.x, c = t & 127, half = t >> 7;
    int v0 = blockIdx.x * 8;
    float bc = bias[c];
    for (int n = 0; n < 8; n++) {
        int v = v0 + n;
        int s = indptr[v], e = indptr[v + 1];
        float acc = 0.f;
        for (int i = s + half; i < e; i += 2) {
            int r = esrc[i];
            acc += hin[r * 128 + c] * dinv[r];
        }
        if (half) buf[c] = acc;
        __syncthreads();
        if (!half) {
            float dv = dinv[v];
            float tot = acc + buf[c] + hin[v * 128 + c] * dv;
            hout[v * 128 + c] = tot * dv + bc;
        }
        __syncthreads();
    }
}

// ---------------- BN column stats (partial sums slab) ----------------
__global__ __launch_bounds__(256) void k_stats(const float* __restrict__ h, float* __restrict__ slab) {
    int t = threadIdx.x, c = t & 127, half = t >> 7;
    float s = 0.f, q = 0.f;
    for (int r = blockIdx.x * 2 + half; r < NN; r += 512) {
        float v = h[r * 128 + c];
        s += v;
        q += v * v;
    }
    __shared__ float red[256];
    red[t] = s;
    __syncthreads();
    if (!half) s += red[t + 128];
    __syncthreads();
    red[t] = q;
    __syncthreads();
    if (!half) {
        q += red[t + 128];
        slab[blockIdx.x * 256 + c] = s;
        slab[blockIdx.x * 256 + 128 + c] = q;
    }
}

__global__ void k_finalize(const float* __restrict__ slab, const float* __restrict__ gamma,
                           const float* __restrict__ beta, float* __restrict__ ss) {
    int c = threadIdx.x;  // 128 threads
    float s = 0.f, q = 0.f;
    for (int b = 0; b < 256; b++) {
        s += slab[b * 256 + c];
        q += slab[b * 256 + 128 + c];
    }
    float mu = s * (1.f / NN);
    float var = q * (1.f / NN) - mu * mu;
    float sc = gamma[c] * rsqrtf(var + 1e-5f);
    ss[c] = sc;
    ss[128 + c] = beta[c] - mu * sc;
}

// ---------------- graph segment bounds from sorted batch ----------------
__global__ __launch_bounds__(256) void k_bounds(const int* __restrict__ batch, int* __restrict__ gstart,
                                                int* __restrict__ gend) {
    int i = blockIdx.x * 256 + threadIdx.x;
    if (i >= NN) return;
    int g = batch[i];
    if (i == 0 || batch[i - 1] != g) gstart[g] = i;
    if (i == NN - 1 || batch[i + 1] != g) gend[g] = i + 1;
}

// ---------------- pooling: pooled[g][c] += relu(bn2(h)) ----------------
__global__ __launch_bounds__(256) void k_pool(const float* __restrict__ h, const int* __restrict__ batch,
                                              const float* __restrict__ ss, float* __restrict__ pooled) {
    int t = threadIdx.x, c = t & 127, half = t >> 7;
    float sc = ss[c], sh = ss[128 + c];
    int r0 = blockIdx.x * 64;
    int g_cur = -1;
    float acc = 0.f;
    for (int i = 0; i < 32; i++) {
        int r = r0 + half + 2 * i;
        int g = batch[r];
        float v = fmaxf(fmaf(h[r * 128 + c], sc, sh), 0.f);
        if (g != g_cur) {
            if (g_cur >= 0) atomicAdd(&pooled[g_cur * 128 + c], acc);
            acc = 0.f;
            g_cur = g;
        }
        acc += v;
    }
    if (g_cur >= 0) atomicAdd(&pooled[g_cur * 128 + c], acc);
}

// ---------------- head: mean, lin1+relu, lin2 ----------------
__global__ __launch_bounds__(256) void k_head(const float* __restrict__ pooled, const int* __restrict__ gstart,
                                              const int* __restrict__ gend, const float* __restrict__ l1W,
                                              const float* __restrict__ l1b, const float* __restrict__ l2W,
                                              const float* __restrict__ l2b, float* __restrict__ out) {
    __shared__ float P[64 * 128];  // 32KB
    __shared__ float Z[64 * 64];   // 16KB
    int t = threadIdx.x;
    for (int i = t; i < 64 * 128; i += 256) {
        int g = i >> 7;
        float cnt = (float)max(gend[g] - gstart[g], 1);
        P[i] = pooled[i] / cnt;
    }
    __syncthreads();
    for (int o = t; o < 64 * 64; o += 256) {
        int g = o >> 6, j = o & 63;
        float s = l1b[j];
        for (int k = 0; k < 128; k++) s += P[g * 128 + k] * l1W[k * 64 + j];
        Z[o] = fmaxf(s, 0.f);
    }
    __syncthreads();
    if (t < 128) {
        int g = t >> 1, cls = t & 1;
        float s = l2b[cls];
        for (int k = 0; k < 64; k++) s += Z[g * 64 + k] * l2W[k * 2 + cls];
        out[g * 2 + cls] = s;
    }
}

extern "C" void kernel_launch(void* const* d_in, const int* in_sizes, int n_in, void* d_out, int out_size,
                              void* d_ws, size_t ws_size, hipStream_t stream) {
    (void)in_sizes; (void)n_in; (void)out_size; (void)ws_size;
    const float* x = (const float*)d_in[0];
    const int* ei = (const int*)d_in[1];
    const int* row = ei;
    const int* col = ei + NE;
    const int* batch = (const int*)d_in[2];
    const float* W1 = (const float*)d_in[3];
    const float* b1 = (const float*)d_in[4];
    const float* W2 = (const float*)d_in[5];
    const float* b2 = (const float*)d_in[6];
    const float* g1 = (const float*)d_in[7];
    const float* be1 = (const float*)d_in[8];
    const float* g2 = (const float*)d_in[9];
    const float* be2 = (const float*)d_in[10];
    const float* l1W = (const float*)d_in[11];
    const float* l1b = (const float*)d_in[12];
    const float* l2W = (const float*)d_in[13];
    const float* l2b = (const float*)d_in[14];
    float* out = (float*)d_out;

    char* ws = (char*)d_ws;
    size_t off = 0;
    auto alloc = [&](size_t bytes) {
        void* p = ws + off;
        off += (bytes + 255) & ~(size_t)255;
        return p;
    };
    float* bufA = (float*)alloc(NN * F * 4);
    float* bufB = (float*)alloc(NN * F * 4);
    int* deg = (int*)alloc(NN * 4);
    float* dinv = (float*)alloc(NN * 4);
    int* indptr = (int*)alloc((NN + 1) * 4);
    int* cursor = (int*)alloc(NN * 4);
    int* esrc = (int*)alloc(NE * 4);
    float* slab = (float*)alloc(256 * 256 * 4);
    float* ss1 = (float*)alloc(256 * 4);
    float* ss2 = (float*)alloc(256 * 4);
    float* pooled = (float*)alloc(NG * F * 4);
    int* gstart = (int*)alloc(NG * 4);
    int* gend = (int*)alloc(NG * 4);

    hipMemsetAsync(deg, 0, NN * 4, stream);
    hipMemsetAsync(pooled, 0, NG * F * 4, stream);
    hipMemsetAsync(gstart, 0, NG * 4, stream);
    hipMemsetAsync(gend, 0, NG * 4, stream);

    k_deg<<<NE / 256, 256, 0, stream>>>(col, deg);
    k_dinv<<<(NN + 255) / 256, 256, 0, stream>>>(deg, dinv);
    k_scan<<<1, 1024, 0, stream>>>(deg, indptr, cursor);
    k_fill<<<NE / 256, 256, 0, stream>>>(row, col, cursor, esrc);

    // layer 1
    k_gemm<false><<<NN / 64, 256, 0, stream>>>(x, W1, bufA, nullptr, nullptr);
    k_agg<<<NN / 8, 256, 0, stream>>>(bufA, indptr, esrc, dinv, b1, bufB);
    k_stats<<<256, 256, 0, stream>>>(bufB, slab);
    k_finalize<<<1, 128, 0, stream>>>(slab, g1, be1, ss1);

    // layer 2 (BN1+ReLU fused into GEMM A-load)
    k_gemm<true><<<NN / 64, 256, 0, stream>>>(bufB, W2, bufA, ss1, ss1 + 128);
    k_agg<<<NN / 8, 256, 0, stream>>>(bufA, indptr, esrc, dinv, b2, bufB);
    k_stats<<<256, 256, 0, stream>>>(bufB, slab);
    k_finalize<<<1, 128, 0, stream>>>(slab, g2, be2, ss2);

    // pooling + head
    k_bounds<<<(NN + 255) / 256, 256, 0, stream>>>(batch, gstart, gend);
    k_pool<<<NN / 64, 256, 0, stream>>>(bufB, batch, ss2, pooled);
    k_head<<<1, 256, 0, stream>>>(pooled, gstart, gend, l1W, l1b, l2W, l2b, out);
}

// Round 2
// 404.663 us; speedup vs baseline: 1.4962x; 1.4962x over previous
//
#include <hip/hip_runtime.h>
#include <hip/hip_fp16.h>

#define NN 40000
#define NE 640000
#define F 128
#define NG 64

// ---------------- degree histogram ----------------
__global__ __launch_bounds__(256) void k_deg(const int* __restrict__ col, int* __restrict__ deg) {
    int e = blockIdx.x * 256 + threadIdx.x;
    if (e < NE) atomicAdd(&deg[col[e]], 1);
}

__global__ __launch_bounds__(256) void k_dinv(const int* __restrict__ deg, float* __restrict__ dinv) {
    int v = blockIdx.x * 256 + threadIdx.x;
    if (v < NN) dinv[v] = rsqrtf((float)(deg[v] + 1));  // +1 self-loop
}

// ---------------- exclusive scan (single block) ----------------
__global__ __launch_bounds__(1024) void k_scan(const int* __restrict__ deg, int* __restrict__ indptr,
                                               int* __restrict__ cursor) {
    __shared__ int part[1024];
    int t = threadIdx.x;
    const int CH = 40;  // 1024*40 >= 40000
    int base = t * CH;
    int s = 0;
    for (int i = 0; i < CH; i++) {
        int idx = base + i;
        if (idx < NN) s += deg[idx];
    }
    part[t] = s;
    __syncthreads();
    for (int off = 1; off < 1024; off <<= 1) {
        int add = (t >= off) ? part[t - off] : 0;
        __syncthreads();
        part[t] += add;
        __syncthreads();
    }
    int run = (t == 0) ? 0 : part[t - 1];
    for (int i = 0; i < CH; i++) {
        int idx = base + i;
        if (idx < NN) {
            indptr[idx] = run;
            cursor[idx] = run;
            run += deg[idx];
        }
    }
    if (t == 1023) indptr[NN] = part[1023];
}

// ---------------- CSR fill ----------------
__global__ __launch_bounds__(256) void k_fill(const int* __restrict__ row, const int* __restrict__ col,
                                              int* __restrict__ cursor, int* __restrict__ esrc) {
    int e = blockIdx.x * 256 + threadIdx.x;
    if (e < NE) {
        int c = col[e];
        int slot = atomicAdd(&cursor[c], 1);
        esrc[slot] = row[e];
    }
}

// ---------------- GEMM: G16[r] = fp16( (act(A) @ W)[r] * dinv[r] ) ----------------
// act = identity (layer1) or BN+ReLU with scale/shift (layer2 input)
template <bool BN>
__global__ __launch_bounds__(256) void k_gemm(const float* __restrict__ A, const float* __restrict__ W,
                                              unsigned int* __restrict__ G, const float* __restrict__ dinv,
                                              const float* __restrict__ scale, const float* __restrict__ shift) {
    __shared__ float Ws[128 * 128];
    int t = threadIdx.x;
    {
        const float4* W4 = (const float4*)W;
        float4* Ws4 = (float4*)Ws;
#pragma unroll
        for (int i = 0; i < 16; i++) Ws4[t + i * 256] = W4[t + i * 256];
    }
    __syncthreads();
    int r0 = blockIdx.x * 64;
    int cg = t & 31, rg = t >> 5;
    int c0 = cg * 4;
    float acc[8][4];
#pragma unroll
    for (int i = 0; i < 8; i++)
#pragma unroll
        for (int j = 0; j < 4; j++) acc[i][j] = 0.f;

    for (int k = 0; k < 128; k += 4) {
        float4 w0 = *(const float4*)&Ws[(k + 0) * 128 + c0];
        float4 w1 = *(const float4*)&Ws[(k + 1) * 128 + c0];
        float4 w2 = *(const float4*)&Ws[(k + 2) * 128 + c0];
        float4 w3 = *(const float4*)&Ws[(k + 3) * 128 + c0];
        float4 sc4, sh4;
        if (BN) {
            sc4 = *(const float4*)&scale[k];
            sh4 = *(const float4*)&shift[k];
        }
#pragma unroll
        for (int i = 0; i < 8; i++) {
            int r = r0 + rg + i * 8;
            float4 a = *(const float4*)&A[r * 128 + k];
            if (BN) {
                a.x = fmaxf(fmaf(a.x, sc4.x, sh4.x), 0.f);
                a.y = fmaxf(fmaf(a.y, sc4.y, sh4.y), 0.f);
                a.z = fmaxf(fmaf(a.z, sc4.z, sh4.z), 0.f);
                a.w = fmaxf(fmaf(a.w, sc4.w, sh4.w), 0.f);
            }
            acc[i][0] += a.x * w0.x + a.y * w1.x + a.z * w2.x + a.w * w3.x;
            acc[i][1] += a.x * w0.y + a.y * w1.y + a.z * w2.y + a.w * w3.y;
            acc[i][2] += a.x * w0.z + a.y * w1.z + a.z * w2.z + a.w * w3.z;
            acc[i][3] += a.x * w0.w + a.y * w1.w + a.z * w2.w + a.w * w3.w;
        }
    }
#pragma unroll
    for (int i = 0; i < 8; i++) {
        int r = r0 + rg + i * 8;
        float dv = dinv[r];
        __half2 h0 = __floats2half2_rn(acc[i][0] * dv, acc[i][1] * dv);
        __half2 h1 = __floats2half2_rn(acc[i][2] * dv, acc[i][3] * dv);
        uint2 pk = make_uint2(*(unsigned int*)&h0, *(unsigned int*)&h1);
        *(uint2*)&G[r * 64 + (c0 >> 1)] = pk;
    }
}

// ---------------- aggregation: out[v] = (sum_in g[r] + g[v]) * dinv[v] + b ----------------
// g = h*dinv pre-scaled fp16; one wave per node, 2 cols per lane, 2 edges in flight.
__global__ __launch_bounds__(256) void k_agg(const unsigned int* __restrict__ g16,
                                             const int* __restrict__ indptr, const int* __restrict__ esrc,
                                             const float* __restrict__ dinv, const float* __restrict__ bias,
                                             float* __restrict__ hout) {
    int t = threadIdx.x;
    int w = t >> 6, l = t & 63;
    int v = blockIdx.x * 4 + w;
    int s = indptr[v], e = indptr[v + 1];
    float a0 = 0.f, a1 = 0.f, b0 = 0.f, b1 = 0.f;
    int i = s;
    for (; i + 1 < e; i += 2) {
        int ra = esrc[i], rb = esrc[i + 1];
        unsigned int ua = g16[ra * 64 + l];
        unsigned int ub = g16[rb * 64 + l];
        __half2 ha = *(__half2*)&ua;
        __half2 hb = *(__half2*)&ub;
        a0 += __low2float(ha); a1 += __high2float(ha);
        b0 += __low2float(hb); b1 += __high2float(hb);
    }
    if (i < e) {
        unsigned int ua = g16[esrc[i] * 64 + l];
        __half2 ha = *(__half2*)&ua;
        a0 += __low2float(ha); a1 += __high2float(ha);
    }
    // self-loop
    unsigned int us = g16[v * 64 + l];
    __half2 hs = *(__half2*)&us;
    a0 += __low2float(hs); a1 += __high2float(hs);
    float dv = dinv[v];
    float2 bi = *(const float2*)&bias[2 * l];
    *(float2*)&hout[v * 128 + 2 * l] = make_float2((a0 + b0) * dv + bi.x, (a1 + b1) * dv + bi.y);
}

// ---------------- BN column stats (float4 vectorized, partial sums slab) ----------------
__global__ __launch_bounds__(256) void k_stats(const float* __restrict__ h, float* __restrict__ slab) {
    int t = threadIdx.x;
    int c4 = t & 31, rs = t >> 5;  // 32 quads per row, 8 row-subgroups
    float sx = 0, sy = 0, sz = 0, sw = 0, qx = 0, qy = 0, qz = 0, qw = 0;
    for (int r = blockIdx.x * 8 + rs; r < NN; r += 1024) {
        float4 v = *(const float4*)&h[r * 128 + c4 * 4];
        sx += v.x; sy += v.y; sz += v.z; sw += v.w;
        qx += v.x * v.x; qy += v.y * v.y; qz += v.z * v.z; qw += v.w * v.w;
    }
    __shared__ float red[256][4];
    red[t][0] = sx; red[t][1] = sy; red[t][2] = sz; red[t][3] = sw;
    __syncthreads();
    if (rs < 4) { for (int j = 0; j < 4; j++) red[t][j] += red[t + 128][j]; }
    __syncthreads();
    if (rs < 2) { for (int j = 0; j < 4; j++) red[t][j] += red[t + 64][j]; }
    __syncthreads();
    if (rs < 1) {
        for (int j = 0; j < 4; j++) slab[blockIdx.x * 256 + c4 * 4 + j] = red[t][j] + red[t + 32][j];
    }
    __syncthreads();
    red[t][0] = qx; red[t][1] = qy; red[t][2] = qz; red[t][3] = qw;
    __syncthreads();
    if (rs < 4) { for (int j = 0; j < 4; j++) red[t][j] += red[t + 128][j]; }
    __syncthreads();
    if (rs < 2) { for (int j = 0; j < 4; j++) red[t][j] += red[t + 64][j]; }
    __syncthreads();
    if (rs < 1) {
        for (int j = 0; j < 4; j++) slab[blockIdx.x * 256 + 128 + c4 * 4 + j] = red[t][j] + red[t + 32][j];
    }
}

__global__ void k_finalize(const float* __restrict__ slab, const float* __restrict__ gamma,
                           const float* __restrict__ beta, float* __restrict__ ss) {
    int c = threadIdx.x;  // 128 threads
    float s = 0.f, q = 0.f;
    for (int b = 0; b < 128; b++) {
        s += slab[b * 256 + c];
        q += slab[b * 256 + 128 + c];
    }
    float mu = s * (1.f / NN);
    float var = q * (1.f / NN) - mu * mu;
    float sc = gamma[c] * rsqrtf(var + 1e-5f);
    ss[c] = sc;
    ss[128 + c] = beta[c] - mu * sc;
}

// ---------------- graph segment bounds from sorted batch ----------------
__global__ __launch_bounds__(256) void k_bounds(const int* __restrict__ batch, int* __restrict__ gstart,
                                                int* __restrict__ gend) {
    int i = blockIdx.x * 256 + threadIdx.x;
    if (i >= NN) return;
    int g = batch[i];
    if (i == 0 || batch[i - 1] != g) gstart[g] = i;
    if (i == NN - 1 || batch[i + 1] != g) gend[g] = i + 1;
}

// ---------------- pooling: pooled[g][c] += relu(bn2(h)) ----------------
__global__ __launch_bounds__(256) void k_pool(const float* __restrict__ h, const int* __restrict__ batch,
                                              const float* __restrict__ ss, float* __restrict__ pooled) {
    int t = threadIdx.x, c = t & 127, half = t >> 7;
    float sc = ss[c], sh = ss[128 + c];
    int r0 = blockIdx.x * 64;
    int g_cur = -1;
    float acc = 0.f;
    for (int i = 0; i < 32; i++) {
        int r = r0 + half + 2 * i;
        int g = batch[r];
        float v = fmaxf(fmaf(h[r * 128 + c], sc, sh), 0.f);
        if (g != g_cur) {
            if (g_cur >= 0) atomicAdd(&pooled[g_cur * 128 + c], acc);
            acc = 0.f;
            g_cur = g;
        }
        acc += v;
    }
    if (g_cur >= 0) atomicAdd(&pooled[g_cur * 128 + c], acc);
}

// ---------------- head: mean, lin1+relu, lin2 ----------------
__global__ __launch_bounds__(256) void k_head(const float* __restrict__ pooled, const int* __restrict__ gstart,
                                              const int* __restrict__ gend, const float* __restrict__ l1W,
                                              const float* __restrict__ l1b, const float* __restrict__ l2W,
                                              const float* __restrict__ l2b, float* __restrict__ out) {
    __shared__ float P[64 * 128];  // 32KB
    __shared__ float Z[64 * 64];   // 16KB
    int t = threadIdx.x;
    for (int i = t; i < 64 * 128; i += 256) {
        int g = i >> 7;
        float cnt = (float)max(gend[g] - gstart[g], 1);
        P[i] = pooled[i] / cnt;
    }
    __syncthreads();
    for (int o = t; o < 64 * 64; o += 256) {
        int g = o >> 6, j = o & 63;
        float s = l1b[j];
        for (int k = 0; k < 128; k++) s += P[g * 128 + k] * l1W[k * 64 + j];
        Z[o] = fmaxf(s, 0.f);
    }
    __syncthreads();
    if (t < 128) {
        int g = t >> 1, cls = t & 1;
        float s = l2b[cls];
        for (int k = 0; k < 64; k++) s += Z[g * 64 + k] * l2W[k * 2 + cls];
        out[g * 2 + cls] = s;
    }
}

extern "C" void kernel_launch(void* const* d_in, const int* in_sizes, int n_in, void* d_out, int out_size,
                              void* d_ws, size_t ws_size, hipStream_t stream) {
    (void)in_sizes; (void)n_in; (void)out_size; (void)ws_size;
    const float* x = (const float*)d_in[0];
    const int* ei = (const int*)d_in[1];
    const int* row = ei;
    const int* col = ei + NE;
    const int* batch = (const int*)d_in[2];
    const float* W1 = (const float*)d_in[3];
    const float* b1 = (const float*)d_in[4];
    const float* W2 = (const float*)d_in[5];
    const float* b2 = (const float*)d_in[6];
    const float* g1 = (const float*)d_in[7];
    const float* be1 = (const float*)d_in[8];
    const float* g2 = (const float*)d_in[9];
    const float* be2 = (const float*)d_in[10];
    const float* l1W = (const float*)d_in[11];
    const float* l1b = (const float*)d_in[12];
    const float* l2W = (const float*)d_in[13];
    const float* l2b = (const float*)d_in[14];
    float* out = (float*)d_out;

    char* ws = (char*)d_ws;
    size_t off = 0;
    auto alloc = [&](size_t bytes) {
        void* p = ws + off;
        off += (bytes + 255) & ~(size_t)255;
        return p;
    };
    unsigned int* g16 = (unsigned int*)alloc(NN * 64 * 4);  // packed fp16 pairs
    float* bufB = (float*)alloc(NN * F * 4);                // fp32 agg output
    int* deg = (int*)alloc(NN * 4);
    float* dinv = (float*)alloc(NN * 4);
    int* indptr = (int*)alloc((NN + 1) * 4);
    int* cursor = (int*)alloc(NN * 4);
    int* esrc = (int*)alloc(NE * 4);
    float* slab = (float*)alloc(128 * 256 * 4);
    float* ss1 = (float*)alloc(256 * 4);
    float* ss2 = (float*)alloc(256 * 4);
    float* pooled = (float*)alloc(NG * F * 4);
    int* gstart = (int*)alloc(NG * 4);
    int* gend = (int*)alloc(NG * 4);

    hipMemsetAsync(deg, 0, NN * 4, stream);
    hipMemsetAsync(pooled, 0, NG * F * 4, stream);
    hipMemsetAsync(gstart, 0, NG * 4, stream);
    hipMemsetAsync(gend, 0, NG * 4, stream);

    k_deg<<<NE / 256, 256, 0, stream>>>(col, deg);
    k_dinv<<<(NN + 255) / 256, 256, 0, stream>>>(deg, dinv);
    k_scan<<<1, 1024, 0, stream>>>(deg, indptr, cursor);
    k_fill<<<NE / 256, 256, 0, stream>>>(row, col, cursor, esrc);

    // layer 1
    k_gemm<false><<<NN / 64, 256, 0, stream>>>(x, W1, g16, dinv, nullptr, nullptr);
    k_agg<<<NN / 4, 256, 0, stream>>>(g16, indptr, esrc, dinv, b1, bufB);
    k_stats<<<128, 256, 0, stream>>>(bufB, slab);
    k_finalize<<<1, 128, 0, stream>>>(slab, g1, be1, ss1);

    // layer 2 (BN1+ReLU fused into GEMM A-load)
    k_gemm<true><<<NN / 64, 256, 0, stream>>>(bufB, W2, g16, dinv, ss1, ss1 + 128);
    k_agg<<<NN / 4, 256, 0, stream>>>(g16, indptr, esrc, dinv, b2, bufB);
    k_stats<<<128, 256, 0, stream>>>(bufB, slab);
    k_finalize<<<1, 128, 0, stream>>>(slab, g2, be2, ss2);

    // pooling + head
    k_bounds<<<(NN + 255) / 256, 256, 0, stream>>>(batch, gstart, gend);
    k_pool<<<NN / 64, 256, 0, stream>>>(bufB, batch, ss2, pooled);
    k_head<<<1, 256, 0, stream>>>(pooled, gstart, gend, l1W, l1b, l2W, l2b, out);
}

// Round 3
// 291.682 us; speedup vs baseline: 2.0757x; 1.3873x over previous
//
#include <hip/hip_runtime.h>
#include <hip/hip_fp16.h>

#define NN 40000
#define NE 640000
#define F 128
#define NG 64
#define SCAN_NB 157  // ceil(40000/256)

// ---------------- degree histogram ----------------
__global__ __launch_bounds__(256) void k_deg(const int* __restrict__ col, int* __restrict__ deg) {
    int e = blockIdx.x * 256 + threadIdx.x;
    if (e < NE) atomicAdd(&deg[col[e]], 1);
}

// ---------------- 3-phase parallel exclusive scan ----------------
__global__ __launch_bounds__(256) void k_scan1(const int* __restrict__ deg, int* __restrict__ partial) {
    __shared__ int sp[256];
    int t = threadIdx.x;
    int i = blockIdx.x * 256 + t;
    sp[t] = (i < NN) ? deg[i] : 0;
    __syncthreads();
#pragma unroll
    for (int off = 128; off > 0; off >>= 1) {
        if (t < off) sp[t] += sp[t + off];
        __syncthreads();
    }
    if (t == 0) partial[blockIdx.x] = sp[0];
}

__global__ __launch_bounds__(256) void k_scan2(const int* __restrict__ partial, int* __restrict__ bsum,
                                               int* __restrict__ indptr) {
    __shared__ int sp[256];
    int t = threadIdx.x;
    int v = (t < SCAN_NB) ? partial[t] : 0;
    sp[t] = v;
    __syncthreads();
#pragma unroll
    for (int off = 1; off < 256; off <<= 1) {
        int add = (t >= off) ? sp[t - off] : 0;
        __syncthreads();
        sp[t] += add;
        __syncthreads();
    }
    if (t < SCAN_NB) bsum[t] = sp[t] - v;
    if (t == SCAN_NB - 1) indptr[NN] = sp[t];
}

__global__ __launch_bounds__(256) void k_scan3(const int* __restrict__ deg, const int* __restrict__ bsum,
                                               int* __restrict__ indptr, int* __restrict__ cursor,
                                               float* __restrict__ dinv) {
    __shared__ int sd[256];
    int t = threadIdx.x;
    int i = blockIdx.x * 256 + t;
    int d = (i < NN) ? deg[i] : 0;
    sd[t] = d;
    __syncthreads();
#pragma unroll
    for (int off = 1; off < 256; off <<= 1) {
        int add = (t >= off) ? sd[t - off] : 0;
        __syncthreads();
        sd[t] += add;
        __syncthreads();
    }
    if (i < NN) {
        int excl = bsum[blockIdx.x] + sd[t] - d;
        indptr[i] = excl;
        cursor[i] = excl;
        dinv[i] = rsqrtf((float)(d + 1));
    }
}

// ---------------- CSR fill ----------------
__global__ __launch_bounds__(256) void k_fill(const int* __restrict__ row, const int* __restrict__ col,
                                              int* __restrict__ cursor, int* __restrict__ esrc) {
    int e = blockIdx.x * 256 + threadIdx.x;
    if (e < NE) {
        int c = col[e];
        int slot = atomicAdd(&cursor[c], 1);
        esrc[slot] = row[e];
    }
}

// ---------------- GEMM: G16[r] = fp16( (act(A) @ W)[r] * dinv[r] ) ----------------
template <bool BN>
__global__ __launch_bounds__(256) void k_gemm(const float* __restrict__ A, const float* __restrict__ W,
                                              unsigned int* __restrict__ G, const float* __restrict__ dinv,
                                              const float* __restrict__ scale, const float* __restrict__ shift) {
    __shared__ float Ws[128 * 128];
    int t = threadIdx.x;
    {
        const float4* W4 = (const float4*)W;
        float4* Ws4 = (float4*)Ws;
#pragma unroll
        for (int i = 0; i < 16; i++) Ws4[t + i * 256] = W4[t + i * 256];
    }
    __syncthreads();
    int r0 = blockIdx.x * 64;
    int cg = t & 31, rg = t >> 5;
    int c0 = cg * 4;
    float acc[8][4];
#pragma unroll
    for (int i = 0; i < 8; i++)
#pragma unroll
        for (int j = 0; j < 4; j++) acc[i][j] = 0.f;

    for (int k = 0; k < 128; k += 4) {
        float4 w0 = *(const float4*)&Ws[(k + 0) * 128 + c0];
        float4 w1 = *(const float4*)&Ws[(k + 1) * 128 + c0];
        float4 w2 = *(const float4*)&Ws[(k + 2) * 128 + c0];
        float4 w3 = *(const float4*)&Ws[(k + 3) * 128 + c0];
        float4 sc4, sh4;
        if (BN) {
            sc4 = *(const float4*)&scale[k];
            sh4 = *(const float4*)&shift[k];
        }
#pragma unroll
        for (int i = 0; i < 8; i++) {
            int r = r0 + rg + i * 8;
            float4 a = *(const float4*)&A[r * 128 + k];
            if (BN) {
                a.x = fmaxf(fmaf(a.x, sc4.x, sh4.x), 0.f);
                a.y = fmaxf(fmaf(a.y, sc4.y, sh4.y), 0.f);
                a.z = fmaxf(fmaf(a.z, sc4.z, sh4.z), 0.f);
                a.w = fmaxf(fmaf(a.w, sc4.w, sh4.w), 0.f);
            }
            acc[i][0] += a.x * w0.x + a.y * w1.x + a.z * w2.x + a.w * w3.x;
            acc[i][1] += a.x * w0.y + a.y * w1.y + a.z * w2.y + a.w * w3.y;
            acc[i][2] += a.x * w0.z + a.y * w1.z + a.z * w2.z + a.w * w3.z;
            acc[i][3] += a.x * w0.w + a.y * w1.w + a.z * w2.w + a.w * w3.w;
        }
    }
#pragma unroll
    for (int i = 0; i < 8; i++) {
        int r = r0 + rg + i * 8;
        float dv = dinv[r];
        __half2 h0 = __floats2half2_rn(acc[i][0] * dv, acc[i][1] * dv);
        __half2 h1 = __floats2half2_rn(acc[i][2] * dv, acc[i][3] * dv);
        uint2 pk = make_uint2(*(unsigned int*)&h0, *(unsigned int*)&h1);
        *(uint2*)&G[r * 64 + (c0 >> 1)] = pk;
    }
}

// ---------------- aggregation: out[v] = (sum_in g[r] + g[v]) * dinv[v] + b ----------------
// g = h*dinv pre-scaled fp16; one wave per node, 2 cols per lane, 4 edges in flight.
__global__ __launch_bounds__(256) void k_agg(const unsigned int* __restrict__ g16,
                                             const int* __restrict__ indptr, const int* __restrict__ esrc,
                                             const float* __restrict__ dinv, const float* __restrict__ bias,
                                             float* __restrict__ hout) {
    int t = threadIdx.x;
    int w = t >> 6, l = t & 63;
    int v = blockIdx.x * 4 + w;
    int s = indptr[v], e = indptr[v + 1];
    float a0 = 0.f, a1 = 0.f, b0 = 0.f, b1 = 0.f;
    float c0 = 0.f, c1 = 0.f, d0 = 0.f, d1 = 0.f;
    int i = s;
    for (; i + 3 < e; i += 4) {
        int ra = esrc[i], rb = esrc[i + 1], rc = esrc[i + 2], rd = esrc[i + 3];
        unsigned int ua = g16[ra * 64 + l];
        unsigned int ub = g16[rb * 64 + l];
        unsigned int uc = g16[rc * 64 + l];
        unsigned int ud = g16[rd * 64 + l];
        __half2 ha = *(__half2*)&ua;
        __half2 hb = *(__half2*)&ub;
        __half2 hc = *(__half2*)&uc;
        __half2 hd = *(__half2*)&ud;
        a0 += __low2float(ha); a1 += __high2float(ha);
        b0 += __low2float(hb); b1 += __high2float(hb);
        c0 += __low2float(hc); c1 += __high2float(hc);
        d0 += __low2float(hd); d1 += __high2float(hd);
    }
    for (; i < e; i++) {
        unsigned int ua = g16[esrc[i] * 64 + l];
        __half2 ha = *(__half2*)&ua;
        a0 += __low2float(ha); a1 += __high2float(ha);
    }
    // self-loop
    unsigned int us = g16[v * 64 + l];
    __half2 hs = *(__half2*)&us;
    a0 += __low2float(hs); a1 += __high2float(hs);
    float dv = dinv[v];
    float2 bi = *(const float2*)&bias[2 * l];
    *(float2*)&hout[v * 128 + 2 * l] =
        make_float2(((a0 + b0) + (c0 + d0)) * dv + bi.x, ((a1 + b1) + (c1 + d1)) * dv + bi.y);
}

// ---------------- BN column stats (float4 vectorized, partial sums slab) ----------------
__global__ __launch_bounds__(256) void k_stats(const float* __restrict__ h, float* __restrict__ slab) {
    int t = threadIdx.x;
    int c4 = t & 31, rs = t >> 5;  // 32 quads per row, 8 row-subgroups
    float sx = 0, sy = 0, sz = 0, sw = 0, qx = 0, qy = 0, qz = 0, qw = 0;
    for (int r = blockIdx.x * 8 + rs; r < NN; r += 1024) {
        float4 v = *(const float4*)&h[r * 128 + c4 * 4];
        sx += v.x; sy += v.y; sz += v.z; sw += v.w;
        qx += v.x * v.x; qy += v.y * v.y; qz += v.z * v.z; qw += v.w * v.w;
    }
    __shared__ float red[256][4];
    red[t][0] = sx; red[t][1] = sy; red[t][2] = sz; red[t][3] = sw;
    __syncthreads();
    if (rs < 4) { for (int j = 0; j < 4; j++) red[t][j] += red[t + 128][j]; }
    __syncthreads();
    if (rs < 2) { for (int j = 0; j < 4; j++) red[t][j] += red[t + 64][j]; }
    __syncthreads();
    if (rs < 1) {
        for (int j = 0; j < 4; j++) slab[blockIdx.x * 256 + c4 * 4 + j] = red[t][j] + red[t + 32][j];
    }
    __syncthreads();
    red[t][0] = qx; red[t][1] = qy; red[t][2] = qz; red[t][3] = qw;
    __syncthreads();
    if (rs < 4) { for (int j = 0; j < 4; j++) red[t][j] += red[t + 128][j]; }
    __syncthreads();
    if (rs < 2) { for (int j = 0; j < 4; j++) red[t][j] += red[t + 64][j]; }
    __syncthreads();
    if (rs < 1) {
        for (int j = 0; j < 4; j++) slab[blockIdx.x * 256 + 128 + c4 * 4 + j] = red[t][j] + red[t + 32][j];
    }
}

__global__ void k_finalize(const float* __restrict__ slab, const float* __restrict__ gamma,
                           const float* __restrict__ beta, float* __restrict__ ss) {
    int c = threadIdx.x;  // 128 threads
    float s = 0.f, q = 0.f;
    for (int b = 0; b < 128; b++) {
        s += slab[b * 256 + c];
        q += slab[b * 256 + 128 + c];
    }
    float mu = s * (1.f / NN);
    float var = q * (1.f / NN) - mu * mu;
    float sc = gamma[c] * rsqrtf(var + 1e-5f);
    ss[c] = sc;
    ss[128 + c] = beta[c] - mu * sc;
}

// ---------------- graph segment bounds from sorted batch ----------------
__global__ __launch_bounds__(256) void k_bounds(const int* __restrict__ batch, int* __restrict__ gstart,
                                                int* __restrict__ gend) {
    int i = blockIdx.x * 256 + threadIdx.x;
    if (i >= NN) return;
    int g = batch[i];
    if (i == 0 || batch[i - 1] != g) gstart[g] = i;
    if (i == NN - 1 || batch[i + 1] != g) gend[g] = i + 1;
}

// ---------------- pooling: pooled[g][c] += relu(bn2(h)) ----------------
__global__ __launch_bounds__(256) void k_pool(const float* __restrict__ h, const int* __restrict__ batch,
                                              const float* __restrict__ ss, float* __restrict__ pooled) {
    int t = threadIdx.x, c = t & 127, half = t >> 7;
    float sc = ss[c], sh = ss[128 + c];
    int r0 = blockIdx.x * 64;
    int g_cur = -1;
    float acc = 0.f;
    for (int i = 0; i < 32; i++) {
        int r = r0 + half + 2 * i;
        int g = batch[r];
        float v = fmaxf(fmaf(h[r * 128 + c], sc, sh), 0.f);
        if (g != g_cur) {
            if (g_cur >= 0) atomicAdd(&pooled[g_cur * 128 + c], acc);
            acc = 0.f;
            g_cur = g;
        }
        acc += v;
    }
    if (g_cur >= 0) atomicAdd(&pooled[g_cur * 128 + c], acc);
}

// ---------------- head: mean, lin1+relu, lin2 ----------------
__global__ __launch_bounds__(256) void k_head(const float* __restrict__ pooled, const int* __restrict__ gstart,
                                              const int* __restrict__ gend, const float* __restrict__ l1W,
                                              const float* __restrict__ l1b, const float* __restrict__ l2W,
                                              const float* __restrict__ l2b, float* __restrict__ out) {
    __shared__ float P[64 * 128];  // 32KB
    __shared__ float Z[64 * 64];   // 16KB
    int t = threadIdx.x;
    for (int i = t; i < 64 * 128; i += 256) {
        int g = i >> 7;
        float cnt = (float)max(gend[g] - gstart[g], 1);
        P[i] = pooled[i] / cnt;
    }
    __syncthreads();
    for (int o = t; o < 64 * 64; o += 256) {
        int g = o >> 6, j = o & 63;
        float s = l1b[j];
        for (int k = 0; k < 128; k++) s += P[g * 128 + k] * l1W[k * 64 + j];
        Z[o] = fmaxf(s, 0.f);
    }
    __syncthreads();
    if (t < 128) {
        int g = t >> 1, cls = t & 1;
        float s = l2b[cls];
        for (int k = 0; k < 64; k++) s += Z[g * 64 + k] * l2W[k * 2 + cls];
        out[g * 2 + cls] = s;
    }
}

extern "C" void kernel_launch(void* const* d_in, const int* in_sizes, int n_in, void* d_out, int out_size,
                              void* d_ws, size_t ws_size, hipStream_t stream) {
    (void)in_sizes; (void)n_in; (void)out_size; (void)ws_size;
    const float* x = (const float*)d_in[0];
    const int* ei = (const int*)d_in[1];
    const int* row = ei;
    const int* col = ei + NE;
    const int* batch = (const int*)d_in[2];
    const float* W1 = (const float*)d_in[3];
    const float* b1 = (const float*)d_in[4];
    const float* W2 = (const float*)d_in[5];
    const float* b2 = (const float*)d_in[6];
    const float* g1 = (const float*)d_in[7];
    const float* be1 = (const float*)d_in[8];
    const float* g2 = (const float*)d_in[9];
    const float* be2 = (const float*)d_in[10];
    const float* l1W = (const float*)d_in[11];
    const float* l1b = (const float*)d_in[12];
    const float* l2W = (const float*)d_in[13];
    const float* l2b = (const float*)d_in[14];
    float* out = (float*)d_out;

    char* ws = (char*)d_ws;
    size_t off = 0;
    auto alloc = [&](size_t bytes) {
        void* p = ws + off;
        off += (bytes + 255) & ~(size_t)255;
        return p;
    };
    unsigned int* g16 = (unsigned int*)alloc(NN * 64 * 4);  // packed fp16 pairs
    float* bufB = (float*)alloc(NN * F * 4);                // fp32 agg output
    int* deg = (int*)alloc(NN * 4);
    float* dinv = (float*)alloc(NN * 4);
    int* indptr = (int*)alloc((NN + 1) * 4);
    int* cursor = (int*)alloc(NN * 4);
    int* esrc = (int*)alloc(NE * 4);
    int* partial = (int*)alloc(256 * 4);
    int* bsum = (int*)alloc(256 * 4);
    float* slab = (float*)alloc(128 * 256 * 4);
    float* ss1 = (float*)alloc(256 * 4);
    float* ss2 = (float*)alloc(256 * 4);
    float* pooled = (float*)alloc(NG * F * 4);
    int* gstart = (int*)alloc(NG * 4);
    int* gend = (int*)alloc(NG * 4);

    hipMemsetAsync(deg, 0, NN * 4, stream);
    hipMemsetAsync(pooled, 0, NG * F * 4, stream);
    hipMemsetAsync(gstart, 0, NG * 4, stream);
    hipMemsetAsync(gend, 0, NG * 4, stream);

    k_deg<<<NE / 256, 256, 0, stream>>>(col, deg);
    k_scan1<<<SCAN_NB, 256, 0, stream>>>(deg, partial);
    k_scan2<<<1, 256, 0, stream>>>(partial, bsum, indptr);
    k_scan3<<<SCAN_NB, 256, 0, stream>>>(deg, bsum, indptr, cursor, dinv);
    k_fill<<<NE / 256, 256, 0, stream>>>(row, col, cursor, esrc);

    // layer 1
    k_gemm<false><<<NN / 64, 256, 0, stream>>>(x, W1, g16, dinv, nullptr, nullptr);
    k_agg<<<NN / 4, 256, 0, stream>>>(g16, indptr, esrc, dinv, b1, bufB);
    k_stats<<<128, 256, 0, stream>>>(bufB, slab);
    k_finalize<<<1, 128, 0, stream>>>(slab, g1, be1, ss1);

    // layer 2 (BN1+ReLU fused into GEMM A-load)
    k_gemm<true><<<NN / 64, 256, 0, stream>>>(bufB, W2, g16, dinv, ss1, ss1 + 128);
    k_agg<<<NN / 4, 256, 0, stream>>>(g16, indptr, esrc, dinv, b2, bufB);
    k_stats<<<128, 256, 0, stream>>>(bufB, slab);
    k_finalize<<<1, 128, 0, stream>>>(slab, g2, be2, ss2);

    // pooling + head
    k_bounds<<<(NN + 255) / 256, 256, 0, stream>>>(batch, gstart, gend);
    k_pool<<<NN / 64, 256, 0, stream>>>(bufB, batch, ss2, pooled);
    k_head<<<1, 256, 0, stream>>>(pooled, gstart, gend, l1W, l1b, l2W, l2b, out);
}

// Round 4
// 249.767 us; speedup vs baseline: 2.4241x; 1.1678x over previous
//
#include <hip/hip_runtime.h>
#include <hip/hip_fp16.h>

#define NN 40000
#define NE 640000
#define F 128
#define NG 64
#define SCAN_NB 157  // ceil(40000/256)

typedef _Float16 f16x8 __attribute__((ext_vector_type(8)));
typedef float f32x4 __attribute__((ext_vector_type(4)));

union U4H {
    uint4 u;
    f16x8 h;
};

// ---------------- degree histogram ----------------
__global__ __launch_bounds__(256) void k_deg(const int* __restrict__ col, int* __restrict__ deg) {
    int e = blockIdx.x * 256 + threadIdx.x;
    if (e < NE) atomicAdd(&deg[col[e]], 1);
}

// ---------------- 3-phase parallel exclusive scan ----------------
__global__ __launch_bounds__(256) void k_scan1(const int* __restrict__ deg, int* __restrict__ partial) {
    __shared__ int sp[256];
    int t = threadIdx.x;
    int i = blockIdx.x * 256 + t;
    sp[t] = (i < NN) ? deg[i] : 0;
    __syncthreads();
#pragma unroll
    for (int off = 128; off > 0; off >>= 1) {
        if (t < off) sp[t] += sp[t + off];
        __syncthreads();
    }
    if (t == 0) partial[blockIdx.x] = sp[0];
}

__global__ __launch_bounds__(256) void k_scan2(const int* __restrict__ partial, int* __restrict__ bsum,
                                               int* __restrict__ indptr) {
    __shared__ int sp[256];
    int t = threadIdx.x;
    int v = (t < SCAN_NB) ? partial[t] : 0;
    sp[t] = v;
    __syncthreads();
#pragma unroll
    for (int off = 1; off < 256; off <<= 1) {
        int add = (t >= off) ? sp[t - off] : 0;
        __syncthreads();
        sp[t] += add;
        __syncthreads();
    }
    if (t < SCAN_NB) bsum[t] = sp[t] - v;
    if (t == SCAN_NB - 1) indptr[NN] = sp[t];
}

__global__ __launch_bounds__(256) void k_scan3(const int* __restrict__ deg, const int* __restrict__ bsum,
                                               int* __restrict__ indptr, int* __restrict__ cursor,
                                               float* __restrict__ dinv) {
    __shared__ int sd[256];
    int t = threadIdx.x;
    int i = blockIdx.x * 256 + t;
    int d = (i < NN) ? deg[i] : 0;
    sd[t] = d;
    __syncthreads();
#pragma unroll
    for (int off = 1; off < 256; off <<= 1) {
        int add = (t >= off) ? sd[t - off] : 0;
        __syncthreads();
        sd[t] += add;
        __syncthreads();
    }
    if (i < NN) {
        int excl = bsum[blockIdx.x] + sd[t] - d;
        indptr[i] = excl;
        cursor[i] = excl;
        dinv[i] = rsqrtf((float)(d + 1));
    }
}

// ---------------- CSR fill ----------------
__global__ __launch_bounds__(256) void k_fill(const int* __restrict__ row, const int* __restrict__ col,
                                              int* __restrict__ cursor, int* __restrict__ esrc) {
    int e = blockIdx.x * 256 + threadIdx.x;
    if (e < NE) {
        int c = col[e];
        int slot = atomicAdd(&cursor[c], 1);
        esrc[slot] = row[e];
    }
}

// ---------------- W prep: split fp32 W into fp16 hi+lo, transposed + XOR-swizzled LDS image ----------------
// img[0..16383] = Wh, img[16384..32767] = Wl; idx = (c*128 + k) ^ ((c&7)<<3)
__global__ __launch_bounds__(256) void k_wprep(const float* __restrict__ W, _Float16* __restrict__ img) {
    int i = blockIdx.x * 256 + threadIdx.x;  // i = k*128 + c
    int k = i >> 7, c = i & 127;
    float v = W[i];
    _Float16 h = (_Float16)v;
    _Float16 lo = (_Float16)(v - (float)h);
    int idx = (c * 128 + k) ^ ((c & 7) << 3);
    img[idx] = h;
    img[16384 + idx] = lo;
}

// ---------------- MFMA GEMM: G16[r] = fp16( (act(A) @ W)[r] * dinv[r] ) ----------------
// MODE 0: A fp32 (layer-1 input x). MODE 1: A packed fp16 + BN scale/shift + ReLU.
// Split-fp16: D = Ah*Wh + Al*Wh + Ah*Wl (error ~ fp32).
template <int MODE>
__global__ __launch_bounds__(256) void k_mgemm(const void* __restrict__ Ain, const uint4* __restrict__ wimg,
                                               const float* __restrict__ ss, const float* __restrict__ dinv,
                                               unsigned short* __restrict__ G) {
    __shared__ _Float16 WT[2][16384];  // 64 KB
    int t = threadIdx.x;
    {
        uint4* dst = (uint4*)&WT[0][0];
#pragma unroll
        for (int i = 0; i < 16; i++) dst[i * 256 + t] = wimg[i * 256 + t];
    }
    __syncthreads();
    int w = t >> 6, l = t & 63;
    int r0w = blockIdx.x * 64 + w * 16;
    int lrow = l & 15, lk = l >> 4;
    int arow = r0w + lrow;

    U4H ah[4], al[4];
    if (MODE == 0) {
        const float* A = (const float*)Ain;
#pragma unroll
        for (int kk = 0; kk < 4; kk++) {
            int k0 = kk * 32 + lk * 8;
            float4 f0 = *(const float4*)&A[arow * 128 + k0];
            float4 f1 = *(const float4*)&A[arow * 128 + k0 + 4];
            float v[8] = {f0.x, f0.y, f0.z, f0.w, f1.x, f1.y, f1.z, f1.w};
#pragma unroll
            for (int j = 0; j < 8; j++) {
                _Float16 h = (_Float16)v[j];
                ah[kk].h[j] = h;
                al[kk].h[j] = (_Float16)(v[j] - (float)h);
            }
        }
    } else {
        const unsigned int* A = (const unsigned int*)Ain;
#pragma unroll
        for (int kk = 0; kk < 4; kk++) {
            int k0 = kk * 32 + lk * 8;
            uint4 u = *(const uint4*)&A[arow * 64 + (k0 >> 1)];
            unsigned int uu[4] = {u.x, u.y, u.z, u.w};
#pragma unroll
            for (int p = 0; p < 4; p++) {
                __half2 hp = *(__half2*)&uu[p];
                int k = k0 + 2 * p;
                float v0 = fmaxf(fmaf(__low2float(hp), ss[k], ss[128 + k]), 0.f);
                float v1 = fmaxf(fmaf(__high2float(hp), ss[k + 1], ss[129 + k]), 0.f);
                _Float16 h0 = (_Float16)v0;
                _Float16 h1 = (_Float16)v1;
                ah[kk].h[2 * p] = h0;
                ah[kk].h[2 * p + 1] = h1;
                al[kk].h[2 * p] = (_Float16)(v0 - (float)h0);
                al[kk].h[2 * p + 1] = (_Float16)(v1 - (float)h1);
            }
        }
    }

    f32x4 acc[8];
#pragma unroll
    for (int ct = 0; ct < 8; ct++) acc[ct] = (f32x4){0.f, 0.f, 0.f, 0.f};

#pragma unroll
    for (int kk = 0; kk < 4; kk++) {
        int k0 = kk * 32 + lk * 8;
#pragma unroll
        for (int ct = 0; ct < 8; ct++) {
            int c = ct * 16 + lrow;
            int idx = (c * 128 + k0) ^ ((c & 7) << 3);
            U4H bh, bl;
            bh.h = *(f16x8*)&WT[0][idx];
            bl.h = *(f16x8*)&WT[1][idx];
            acc[ct] = __builtin_amdgcn_mfma_f32_16x16x32_f16(ah[kk].h, bh.h, acc[ct], 0, 0, 0);
            acc[ct] = __builtin_amdgcn_mfma_f32_16x16x32_f16(al[kk].h, bh.h, acc[ct], 0, 0, 0);
            acc[ct] = __builtin_amdgcn_mfma_f32_16x16x32_f16(ah[kk].h, bl.h, acc[ct], 0, 0, 0);
        }
    }

    float dv[4];
#pragma unroll
    for (int j = 0; j < 4; j++) dv[j] = dinv[r0w + lk * 4 + j];
#pragma unroll
    for (int ct = 0; ct < 8; ct++) {
        int c = ct * 16 + lrow;
#pragma unroll
        for (int j = 0; j < 4; j++) {
            int r = r0w + lk * 4 + j;
            __half hv = __float2half(acc[ct][j] * dv[j]);
            G[r * 128 + c] = *(unsigned short*)&hv;
        }
    }
}

// ---------------- aggregation: out[v] = fp16( (sum_in g[r] + g[v]) * dinv[v] + b ) ----------------
// g pre-scaled fp16; one wave per node, 2 cols/lane, 8 gathers in flight.
__global__ __launch_bounds__(256) void k_agg(const unsigned int* __restrict__ g16,
                                             const int* __restrict__ indptr, const int* __restrict__ esrc,
                                             const float* __restrict__ dinv, const float* __restrict__ bias,
                                             unsigned int* __restrict__ hout) {
    int t = threadIdx.x;
    int w = t >> 6, l = t & 63;
    int v = blockIdx.x * 4 + w;
    int s = indptr[v], e = indptr[v + 1];
    float a0[8], a1[8];
#pragma unroll
    for (int j = 0; j < 8; j++) { a0[j] = 0.f; a1[j] = 0.f; }
    int i = s;
    for (; i + 7 < e; i += 8) {
        unsigned int u[8];
#pragma unroll
        for (int j = 0; j < 8; j++) u[j] = g16[esrc[i + j] * 64 + l];
#pragma unroll
        for (int j = 0; j < 8; j++) {
            __half2 p = *(__half2*)&u[j];
            a0[j] += __low2float(p);
            a1[j] += __high2float(p);
        }
    }
    for (; i < e; i++) {
        unsigned int u = g16[esrc[i] * 64 + l];
        __half2 p = *(__half2*)&u;
        a0[0] += __low2float(p);
        a1[0] += __high2float(p);
    }
    // self-loop
    {
        unsigned int u = g16[v * 64 + l];
        __half2 p = *(__half2*)&u;
        a0[1] += __low2float(p);
        a1[1] += __high2float(p);
    }
    float s0 = ((a0[0] + a0[1]) + (a0[2] + a0[3])) + ((a0[4] + a0[5]) + (a0[6] + a0[7]));
    float s1 = ((a1[0] + a1[1]) + (a1[2] + a1[3])) + ((a1[4] + a1[5]) + (a1[6] + a1[7]));
    float dvv = dinv[v];
    float2 bi = *(const float2*)&bias[2 * l];
    __half2 o = __floats2half2_rn(s0 * dvv + bi.x, s1 * dvv + bi.y);
    hout[v * 64 + l] = *(unsigned int*)&o;
}

// ---------------- BN column stats over packed fp16 h ----------------
__global__ __launch_bounds__(256) void k_stats(const unsigned int* __restrict__ h, float* __restrict__ slab) {
    int t = threadIdx.x;
    int c4 = t & 31, rs = t >> 5;  // 32 col-quads, 8 row-subgroups
    float sx = 0, sy = 0, sz = 0, sw = 0, qx = 0, qy = 0, qz = 0, qw = 0;
    for (int r = blockIdx.x * 8 + rs; r < NN; r += 1024) {
        uint2 u = *(const uint2*)&h[r * 64 + c4 * 2];
        __half2 p0 = *(__half2*)&u.x;
        __half2 p1 = *(__half2*)&u.y;
        float a = __low2float(p0), b = __high2float(p0), c = __low2float(p1), d = __high2float(p1);
        sx += a; sy += b; sz += c; sw += d;
        qx += a * a; qy += b * b; qz += c * c; qw += d * d;
    }
    __shared__ float red[256][4];
    red[t][0] = sx; red[t][1] = sy; red[t][2] = sz; red[t][3] = sw;
    __syncthreads();
    if (rs < 4) { for (int j = 0; j < 4; j++) red[t][j] += red[t + 128][j]; }
    __syncthreads();
    if (rs < 2) { for (int j = 0; j < 4; j++) red[t][j] += red[t + 64][j]; }
    __syncthreads();
    if (rs < 1) {
        for (int j = 0; j < 4; j++) slab[blockIdx.x * 256 + c4 * 4 + j] = red[t][j] + red[t + 32][j];
    }
    __syncthreads();
    red[t][0] = qx; red[t][1] = qy; red[t][2] = qz; red[t][3] = qw;
    __syncthreads();
    if (rs < 4) { for (int j = 0; j < 4; j++) red[t][j] += red[t + 128][j]; }
    __syncthreads();
    if (rs < 2) { for (int j = 0; j < 4; j++) red[t][j] += red[t + 64][j]; }
    __syncthreads();
    if (rs < 1) {
        for (int j = 0; j < 4; j++) slab[blockIdx.x * 256 + 128 + c4 * 4 + j] = red[t][j] + red[t + 32][j];
    }
}

__global__ void k_finalize(const float* __restrict__ slab, const float* __restrict__ gamma,
                           const float* __restrict__ beta, float* __restrict__ ss) {
    int c = threadIdx.x;  // 128 threads
    float s = 0.f, q = 0.f;
    for (int b = 0; b < 128; b++) {
        s += slab[b * 256 + c];
        q += slab[b * 256 + 128 + c];
    }
    float mu = s * (1.f / NN);
    float var = q * (1.f / NN) - mu * mu;
    float sc = gamma[c] * rsqrtf(var + 1e-5f);
    ss[c] = sc;
    ss[128 + c] = beta[c] - mu * sc;
}

// ---------------- graph segment bounds ----------------
__global__ __launch_bounds__(256) void k_bounds(const int* __restrict__ batch, int* __restrict__ gstart,
                                                int* __restrict__ gend) {
    int i = blockIdx.x * 256 + threadIdx.x;
    if (i >= NN) return;
    int g = batch[i];
    if (i == 0 || batch[i - 1] != g) gstart[g] = i;
    if (i == NN - 1 || batch[i + 1] != g) gend[g] = i + 1;
}

// ---------------- pooling: pooled[g][c] += relu(bn2(h16)) ----------------
__global__ __launch_bounds__(256) void k_pool(const unsigned int* __restrict__ h, const int* __restrict__ batch,
                                              const float* __restrict__ ss, float* __restrict__ pooled) {
    int t = threadIdx.x, c2 = t & 63, q = t >> 6;
    float sc0 = ss[2 * c2], sc1 = ss[2 * c2 + 1];
    float sh0 = ss[128 + 2 * c2], sh1 = ss[129 + 2 * c2];
    int r0 = blockIdx.x * 64;
    int g_cur = -1;
    float a0 = 0.f, a1 = 0.f;
    for (int i = 0; i < 16; i++) {
        int r = r0 + q + 4 * i;
        int g = batch[r];
        unsigned int u = h[r * 64 + c2];
        __half2 p = *(__half2*)&u;
        float v0 = fmaxf(fmaf(__low2float(p), sc0, sh0), 0.f);
        float v1 = fmaxf(fmaf(__high2float(p), sc1, sh1), 0.f);
        if (g != g_cur) {
            if (g_cur >= 0) {
                atomicAdd(&pooled[g_cur * 128 + 2 * c2], a0);
                atomicAdd(&pooled[g_cur * 128 + 2 * c2 + 1], a1);
            }
            a0 = 0.f; a1 = 0.f; g_cur = g;
        }
        a0 += v0; a1 += v1;
    }
    if (g_cur >= 0) {
        atomicAdd(&pooled[g_cur * 128 + 2 * c2], a0);
        atomicAdd(&pooled[g_cur * 128 + 2 * c2 + 1], a1);
    }
}

// ---------------- head ----------------
__global__ __launch_bounds__(256) void k_head(const float* __restrict__ pooled, const int* __restrict__ gstart,
                                              const int* __restrict__ gend, const float* __restrict__ l1W,
                                              const float* __restrict__ l1b, const float* __restrict__ l2W,
                                              const float* __restrict__ l2b, float* __restrict__ out) {
    __shared__ float P[64 * 128];
    __shared__ float Z[64 * 64];
    int t = threadIdx.x;
    for (int i = t; i < 64 * 128; i += 256) {
        int g = i >> 7;
        float cnt = (float)max(gend[g] - gstart[g], 1);
        P[i] = pooled[i] / cnt;
    }
    __syncthreads();
    for (int o = t; o < 64 * 64; o += 256) {
        int g = o >> 6, j = o & 63;
        float s = l1b[j];
        for (int k = 0; k < 128; k++) s += P[g * 128 + k] * l1W[k * 64 + j];
        Z[o] = fmaxf(s, 0.f);
    }
    __syncthreads();
    if (t < 128) {
        int g = t >> 1, cls = t & 1;
        float s = l2b[cls];
        for (int k = 0; k < 64; k++) s += Z[g * 64 + k] * l2W[k * 2 + cls];
        out[g * 2 + cls] = s;
    }
}

extern "C" void kernel_launch(void* const* d_in, const int* in_sizes, int n_in, void* d_out, int out_size,
                              void* d_ws, size_t ws_size, hipStream_t stream) {
    (void)in_sizes; (void)n_in; (void)out_size; (void)ws_size;
    const float* x = (const float*)d_in[0];
    const int* ei = (const int*)d_in[1];
    const int* row = ei;
    const int* col = ei + NE;
    const int* batch = (const int*)d_in[2];
    const float* W1 = (const float*)d_in[3];
    const float* b1 = (const float*)d_in[4];
    const float* W2 = (const float*)d_in[5];
    const float* b2 = (const float*)d_in[6];
    const float* g1 = (const float*)d_in[7];
    const float* be1 = (const float*)d_in[8];
    const float* g2 = (const float*)d_in[9];
    const float* be2 = (const float*)d_in[10];
    const float* l1W = (const float*)d_in[11];
    const float* l1b = (const float*)d_in[12];
    const float* l2W = (const float*)d_in[13];
    const float* l2b = (const float*)d_in[14];
    float* out = (float*)d_out;

    char* ws = (char*)d_ws;
    size_t off = 0;
    auto alloc = [&](size_t bytes) {
        void* p = ws + off;
        off += (bytes + 255) & ~(size_t)255;
        return p;
    };
    unsigned int* g16 = (unsigned int*)alloc(NN * 64 * 4);    // packed fp16 (h*dinv)
    unsigned int* h16a = (unsigned int*)alloc(NN * 64 * 4);   // layer-1 agg out fp16
    unsigned int* h16b = (unsigned int*)alloc(NN * 64 * 4);   // layer-2 agg out fp16
    int* deg = (int*)alloc(NN * 4);
    float* dinv = (float*)alloc(NN * 4);
    int* indptr = (int*)alloc((NN + 1) * 4);
    int* cursor = (int*)alloc(NN * 4);
    int* esrc = (int*)alloc(NE * 4);
    int* partial = (int*)alloc(256 * 4);
    int* bsum = (int*)alloc(256 * 4);
    float* slab = (float*)alloc(128 * 256 * 4);
    float* ss1 = (float*)alloc(256 * 4);
    float* ss2 = (float*)alloc(256 * 4);
    float* pooled = (float*)alloc(NG * F * 4);
    int* gstart = (int*)alloc(NG * 4);
    int* gend = (int*)alloc(NG * 4);
    _Float16* wimg1 = (_Float16*)alloc(32768 * 2);
    _Float16* wimg2 = (_Float16*)alloc(32768 * 2);

    hipMemsetAsync(deg, 0, NN * 4, stream);
    hipMemsetAsync(pooled, 0, NG * F * 4, stream);
    hipMemsetAsync(gstart, 0, NG * 4, stream);
    hipMemsetAsync(gend, 0, NG * 4, stream);

    k_wprep<<<64, 256, 0, stream>>>(W1, wimg1);
    k_wprep<<<64, 256, 0, stream>>>(W2, wimg2);
    k_deg<<<NE / 256, 256, 0, stream>>>(col, deg);
    k_scan1<<<SCAN_NB, 256, 0, stream>>>(deg, partial);
    k_scan2<<<1, 256, 0, stream>>>(partial, bsum, indptr);
    k_scan3<<<SCAN_NB, 256, 0, stream>>>(deg, bsum, indptr, cursor, dinv);
    k_fill<<<NE / 256, 256, 0, stream>>>(row, col, cursor, esrc);

    // layer 1
    k_mgemm<0><<<NN / 64, 256, 0, stream>>>(x, (const uint4*)wimg1, nullptr, dinv, (unsigned short*)g16);
    k_agg<<<NN / 4, 256, 0, stream>>>(g16, indptr, esrc, dinv, b1, h16a);
    k_stats<<<128, 256, 0, stream>>>(h16a, slab);
    k_finalize<<<1, 128, 0, stream>>>(slab, g1, be1, ss1);

    // layer 2 (BN1+ReLU fused into GEMM A-load)
    k_mgemm<1><<<NN / 64, 256, 0, stream>>>(h16a, (const uint4*)wimg2, ss1, dinv, (unsigned short*)g16);
    k_agg<<<NN / 4, 256, 0, stream>>>(g16, indptr, esrc, dinv, b2, h16b);
    k_stats<<<128, 256, 0, stream>>>(h16b, slab);
    k_finalize<<<1, 128, 0, stream>>>(slab, g2, be2, ss2);

    // pooling + head
    k_bounds<<<(NN + 255) / 256, 256, 0, stream>>>(batch, gstart, gend);
    k_pool<<<NN / 64, 256, 0, stream>>>(h16b, batch, ss2, pooled);
    k_head<<<1, 256, 0, stream>>>(pooled, gstart, gend, l1W, l1b, l2W, l2b, out);
}

// Round 5
// 206.560 us; speedup vs baseline: 2.9311x; 1.2092x over previous
//
#include <hip/hip_runtime.h>
#include <hip/hip_fp16.h>

#define NN 40000
#define NE 640000
#define F 128
#define NG 64
#define SCAN_NB 157  // ceil(40000/256)

typedef _Float16 f16x8 __attribute__((ext_vector_type(8)));
typedef float f32x4 __attribute__((ext_vector_type(4)));

union U4H {
    uint4 u;
    f16x8 h;
};

// ---------------- init: zero deg/pooled/slabs + graph bounds (replaces 4 memsets + k_bounds) ----------------
__global__ __launch_bounds__(256) void k_init(const int* __restrict__ batch, int* __restrict__ deg,
                                              float* __restrict__ pooled, float* __restrict__ slabs,
                                              int* __restrict__ gstart, int* __restrict__ gend) {
    int i = blockIdx.x * 256 + threadIdx.x;
    if (i < NN) {
        deg[i] = 0;
        int g = batch[i];
        if (i == 0 || batch[i - 1] != g) gstart[g] = i;
        if (i == NN - 1 || batch[i + 1] != g) gend[g] = i + 1;
    }
    if (i < NG * F) pooled[i] = 0.f;
    if (i < 64 * 128) {
        slabs[i] = 0.f;                // slab1 S
        slabs[8192 + i] = 0.f;         // slab1 Q
        slabs[16384 + i] = 0.f;        // slab2 S
        slabs[24576 + i] = 0.f;        // slab2 Q
    }
}

// ---------------- degree histogram ----------------
__global__ __launch_bounds__(256) void k_deg(const int* __restrict__ col, int* __restrict__ deg) {
    int e = blockIdx.x * 256 + threadIdx.x;
    if (e < NE) atomicAdd(&deg[col[e]], 1);
}

// ---------------- 3-phase parallel exclusive scan ----------------
__global__ __launch_bounds__(256) void k_scan1(const int* __restrict__ deg, int* __restrict__ partial) {
    __shared__ int sp[256];
    int t = threadIdx.x;
    int i = blockIdx.x * 256 + t;
    sp[t] = (i < NN) ? deg[i] : 0;
    __syncthreads();
#pragma unroll
    for (int off = 128; off > 0; off >>= 1) {
        if (t < off) sp[t] += sp[t + off];
        __syncthreads();
    }
    if (t == 0) partial[blockIdx.x] = sp[0];
}

__global__ __launch_bounds__(256) void k_scan2(const int* __restrict__ partial, int* __restrict__ bsum,
                                               int* __restrict__ indptr) {
    __shared__ int sp[256];
    int t = threadIdx.x;
    int v = (t < SCAN_NB) ? partial[t] : 0;
    sp[t] = v;
    __syncthreads();
#pragma unroll
    for (int off = 1; off < 256; off <<= 1) {
        int add = (t >= off) ? sp[t - off] : 0;
        __syncthreads();
        sp[t] += add;
        __syncthreads();
    }
    if (t < SCAN_NB) bsum[t] = sp[t] - v;
    if (t == SCAN_NB - 1) indptr[NN] = sp[t];
}

__global__ __launch_bounds__(256) void k_scan3(const int* __restrict__ deg, const int* __restrict__ bsum,
                                               int* __restrict__ indptr, int* __restrict__ cursor,
                                               float* __restrict__ dinv) {
    __shared__ int sd[256];
    int t = threadIdx.x;
    int i = blockIdx.x * 256 + t;
    int d = (i < NN) ? deg[i] : 0;
    sd[t] = d;
    __syncthreads();
#pragma unroll
    for (int off = 1; off < 256; off <<= 1) {
        int add = (t >= off) ? sd[t - off] : 0;
        __syncthreads();
        sd[t] += add;
        __syncthreads();
    }
    if (i < NN) {
        int excl = bsum[blockIdx.x] + sd[t] - d;
        indptr[i] = excl;
        cursor[i] = excl;
        dinv[i] = rsqrtf((float)(d + 1));
    }
}

// ---------------- CSR fill ----------------
__global__ __launch_bounds__(256) void k_fill(const int* __restrict__ row, const int* __restrict__ col,
                                              int* __restrict__ cursor, int* __restrict__ esrc) {
    int e = blockIdx.x * 256 + threadIdx.x;
    if (e < NE) {
        int c = col[e];
        int slot = atomicAdd(&cursor[c], 1);
        esrc[slot] = row[e];
    }
}

// ---------------- W prep (both layers): split fp32 W into fp16 hi+lo, transposed + XOR-swizzled ----------------
// idx = (c*128 + k) ^ ((c&7)<<3); img[idx] = hi, img[16384+idx] = lo
__global__ __launch_bounds__(256) void k_wprep(const float* __restrict__ W1, const float* __restrict__ W2,
                                               _Float16* __restrict__ img1, _Float16* __restrict__ img2) {
    int i = blockIdx.x * 256 + threadIdx.x;
    const float* W = (i < 16384) ? W1 : W2;
    _Float16* img = (i < 16384) ? img1 : img2;
    int j = i & 16383;
    int k = j >> 7, c = j & 127;
    float v = W[j];
    _Float16 h = (_Float16)v;
    _Float16 lo = (_Float16)(v - (float)h);
    int idx = (c * 128 + k) ^ ((c & 7) << 3);
    img[idx] = h;
    img[16384 + idx] = lo;
}

// ---------------- MFMA GEMM: G16[r] = fp16( (act(A) @ W)[r] * dinv[r] ) ----------------
// MODE 0: A fp32 (layer-1 input x). MODE 1: A packed fp16 + BN scale/shift + ReLU.
// Split-fp16: D = Ah*Wh + Al*Wh + Ah*Wl (error ~ fp32).
template <int MODE>
__global__ __launch_bounds__(256) void k_mgemm(const void* __restrict__ Ain, const uint4* __restrict__ wimg,
                                               const float* __restrict__ ss, const float* __restrict__ dinv,
                                               unsigned short* __restrict__ G) {
    __shared__ _Float16 WT[2][16384];  // 64 KB
    int t = threadIdx.x;
    {
        uint4* dst = (uint4*)&WT[0][0];
#pragma unroll
        for (int i = 0; i < 16; i++) dst[i * 256 + t] = wimg[i * 256 + t];
    }
    __syncthreads();
    int w = t >> 6, l = t & 63;
    int r0w = blockIdx.x * 64 + w * 16;
    int lrow = l & 15, lk = l >> 4;
    int arow = r0w + lrow;

    U4H ah[4], al[4];
    if (MODE == 0) {
        const float* A = (const float*)Ain;
#pragma unroll
        for (int kk = 0; kk < 4; kk++) {
            int k0 = kk * 32 + lk * 8;
            float4 f0 = *(const float4*)&A[arow * 128 + k0];
            float4 f1 = *(const float4*)&A[arow * 128 + k0 + 4];
            float v[8] = {f0.x, f0.y, f0.z, f0.w, f1.x, f1.y, f1.z, f1.w};
#pragma unroll
            for (int j = 0; j < 8; j++) {
                _Float16 h = (_Float16)v[j];
                ah[kk].h[j] = h;
                al[kk].h[j] = (_Float16)(v[j] - (float)h);
            }
        }
    } else {
        const unsigned int* A = (const unsigned int*)Ain;
#pragma unroll
        for (int kk = 0; kk < 4; kk++) {
            int k0 = kk * 32 + lk * 8;
            uint4 u = *(const uint4*)&A[arow * 64 + (k0 >> 1)];
            unsigned int uu[4] = {u.x, u.y, u.z, u.w};
#pragma unroll
            for (int p = 0; p < 4; p++) {
                __half2 hp = *(__half2*)&uu[p];
                int k = k0 + 2 * p;
                float v0 = fmaxf(fmaf(__low2float(hp), ss[k], ss[128 + k]), 0.f);
                float v1 = fmaxf(fmaf(__high2float(hp), ss[k + 1], ss[129 + k]), 0.f);
                _Float16 h0 = (_Float16)v0;
                _Float16 h1 = (_Float16)v1;
                ah[kk].h[2 * p] = h0;
                ah[kk].h[2 * p + 1] = h1;
                al[kk].h[2 * p] = (_Float16)(v0 - (float)h0);
                al[kk].h[2 * p + 1] = (_Float16)(v1 - (float)h1);
            }
        }
    }

    f32x4 acc[8];
#pragma unroll
    for (int ct = 0; ct < 8; ct++) acc[ct] = (f32x4){0.f, 0.f, 0.f, 0.f};

#pragma unroll
    for (int kk = 0; kk < 4; kk++) {
        int k0 = kk * 32 + lk * 8;
#pragma unroll
        for (int ct = 0; ct < 8; ct++) {
            int c = ct * 16 + lrow;
            int idx = (c * 128 + k0) ^ ((c & 7) << 3);
            U4H bh, bl;
            bh.h = *(f16x8*)&WT[0][idx];
            bl.h = *(f16x8*)&WT[1][idx];
            acc[ct] = __builtin_amdgcn_mfma_f32_16x16x32_f16(ah[kk].h, bh.h, acc[ct], 0, 0, 0);
            acc[ct] = __builtin_amdgcn_mfma_f32_16x16x32_f16(al[kk].h, bh.h, acc[ct], 0, 0, 0);
            acc[ct] = __builtin_amdgcn_mfma_f32_16x16x32_f16(ah[kk].h, bl.h, acc[ct], 0, 0, 0);
        }
    }

    float dv[4];
#pragma unroll
    for (int j = 0; j < 4; j++) dv[j] = dinv[r0w + lk * 4 + j];
#pragma unroll
    for (int ct = 0; ct < 8; ct++) {
        int c = ct * 16 + lrow;
#pragma unroll
        for (int j = 0; j < 4; j++) {
            int r = r0w + lk * 4 + j;
            __half hv = __float2half(acc[ct][j] * dv[j]);
            G[r * 128 + c] = *(unsigned short*)&hv;
        }
    }
}

// ---------------- aggregation + fused BN stats ----------------
// out[v] = fp16( (sum_in g[r] + g[v]) * dinv[v] + b ); 4 edge-slots x 16 lanes, uint4 row loads,
// 16 edge-rows in flight; epilogue accumulates column sum/sumsq partials into spread slab.
__device__ __forceinline__ void accum8(float* acc, uint4 u) {
    __half2 p0 = *(__half2*)&u.x, p1 = *(__half2*)&u.y, p2 = *(__half2*)&u.z, p3 = *(__half2*)&u.w;
    acc[0] += __low2float(p0); acc[1] += __high2float(p0);
    acc[2] += __low2float(p1); acc[3] += __high2float(p1);
    acc[4] += __low2float(p2); acc[5] += __high2float(p2);
    acc[6] += __low2float(p3); acc[7] += __high2float(p3);
}

__global__ __launch_bounds__(256) void k_agg(const uint4* __restrict__ g16, const int* __restrict__ indptr,
                                             const int* __restrict__ esrc, const float* __restrict__ dinv,
                                             const float* __restrict__ bias, uint4* __restrict__ hout,
                                             float* __restrict__ slabS, float* __restrict__ slabQ) {
    __shared__ float lsS[4][128];
    __shared__ float lsQ[4][128];
    int t = threadIdx.x;
    int w = t >> 6, l = t & 63;
    int slot = l >> 4, lc = l & 15;  // lane covers cols [8*lc, 8*lc+8)
    int v = blockIdx.x * 4 + w;
    int s = indptr[v], e = indptr[v + 1];
    float acc[8];
#pragma unroll
    for (int j = 0; j < 8; j++) acc[j] = 0.f;

    int i = s;
    for (; i + 15 < e; i += 16) {
        int r0 = esrc[i + slot];
        int r1 = esrc[i + 4 + slot];
        int r2 = esrc[i + 8 + slot];
        int r3 = esrc[i + 12 + slot];
        uint4 u0 = g16[r0 * 16 + lc];
        uint4 u1 = g16[r1 * 16 + lc];
        uint4 u2 = g16[r2 * 16 + lc];
        uint4 u3 = g16[r3 * 16 + lc];
        accum8(acc, u0);
        accum8(acc, u1);
        accum8(acc, u2);
        accum8(acc, u3);
    }
    for (; i + 3 < e; i += 4) {
        int r0 = esrc[i + slot];
        uint4 u0 = g16[r0 * 16 + lc];
        accum8(acc, u0);
    }
    if (i + slot < e) {
        int r0 = esrc[i + slot];
        uint4 u0 = g16[r0 * 16 + lc];
        accum8(acc, u0);
    }
    // cross-slot reduce (slots 0..3 -> all lanes hold totals)
#pragma unroll
    for (int j = 0; j < 8; j++) {
        acc[j] += __shfl_xor(acc[j], 16, 64);
        acc[j] += __shfl_xor(acc[j], 32, 64);
    }
    if (l < 16) {
        // self-loop row
        uint4 us = g16[v * 16 + l];
        accum8(acc, us);
        float dvv = dinv[l >= 0 ? v : 0];
        float4 ba = ((const float4*)bias)[2 * l];
        float4 bb = ((const float4*)bias)[2 * l + 1];
        float vv[8];
        vv[0] = acc[0] * dvv + ba.x; vv[1] = acc[1] * dvv + ba.y;
        vv[2] = acc[2] * dvv + ba.z; vv[3] = acc[3] * dvv + ba.w;
        vv[4] = acc[4] * dvv + bb.x; vv[5] = acc[5] * dvv + bb.y;
        vv[6] = acc[6] * dvv + bb.z; vv[7] = acc[7] * dvv + bb.w;
        __half2 h0 = __floats2half2_rn(vv[0], vv[1]);
        __half2 h1 = __floats2half2_rn(vv[2], vv[3]);
        __half2 h2 = __floats2half2_rn(vv[4], vv[5]);
        __half2 h3 = __floats2half2_rn(vv[6], vv[7]);
        uint4 o;
        o.x = *(unsigned int*)&h0; o.y = *(unsigned int*)&h1;
        o.z = *(unsigned int*)&h2; o.w = *(unsigned int*)&h3;
        hout[v * 16 + l] = o;
#pragma unroll
        for (int j = 0; j < 8; j++) {
            lsS[w][l * 8 + j] = vv[j];
            lsQ[w][l * 8 + j] = vv[j] * vv[j];
        }
    }
    __syncthreads();
    int sb = (blockIdx.x & 63) * 128;
    if (t < 128) {
        float v4 = (lsS[0][t] + lsS[1][t]) + (lsS[2][t] + lsS[3][t]);
        atomicAdd(&slabS[sb + t], v4);
    } else {
        int c = t - 128;
        float v4 = (lsQ[0][c] + lsQ[1][c]) + (lsQ[2][c] + lsQ[3][c]);
        atomicAdd(&slabQ[sb + c], v4);
    }
}

__global__ void k_finalize(const float* __restrict__ slabS, const float* __restrict__ slabQ,
                           const float* __restrict__ gamma, const float* __restrict__ beta,
                           float* __restrict__ ss) {
    int c = threadIdx.x;  // 128 threads
    float s = 0.f, q = 0.f;
    for (int b = 0; b < 64; b++) {
        s += slabS[b * 128 + c];
        q += slabQ[b * 128 + c];
    }
    float mu = s * (1.f / NN);
    float var = q * (1.f / NN) - mu * mu;
    float sc = gamma[c] * rsqrtf(var + 1e-5f);
    ss[c] = sc;
    ss[128 + c] = beta[c] - mu * sc;
}

// ---------------- pooling: pooled[g][c] += relu(bn2(h16)) ----------------
__global__ __launch_bounds__(256) void k_pool(const unsigned int* __restrict__ h, const int* __restrict__ batch,
                                              const float* __restrict__ ss, float* __restrict__ pooled) {
    int t = threadIdx.x, c2 = t & 63, q = t >> 6;
    float sc0 = ss[2 * c2], sc1 = ss[2 * c2 + 1];
    float sh0 = ss[128 + 2 * c2], sh1 = ss[129 + 2 * c2];
    int r0 = blockIdx.x * 64;
    int g_cur = -1;
    float a0 = 0.f, a1 = 0.f;
    for (int i = 0; i < 16; i++) {
        int r = r0 + q + 4 * i;
        int g = batch[r];
        unsigned int u = h[r * 64 + c2];
        __half2 p = *(__half2*)&u;
        float v0 = fmaxf(fmaf(__low2float(p), sc0, sh0), 0.f);
        float v1 = fmaxf(fmaf(__high2float(p), sc1, sh1), 0.f);
        if (g != g_cur) {
            if (g_cur >= 0) {
                atomicAdd(&pooled[g_cur * 128 + 2 * c2], a0);
                atomicAdd(&pooled[g_cur * 128 + 2 * c2 + 1], a1);
            }
            a0 = 0.f; a1 = 0.f; g_cur = g;
        }
        a0 += v0; a1 += v1;
    }
    if (g_cur >= 0) {
        atomicAdd(&pooled[g_cur * 128 + 2 * c2], a0);
        atomicAdd(&pooled[g_cur * 128 + 2 * c2 + 1], a1);
    }
}

// ---------------- head ----------------
__global__ __launch_bounds__(256) void k_head(const float* __restrict__ pooled, const int* __restrict__ gstart,
                                              const int* __restrict__ gend, const float* __restrict__ l1W,
                                              const float* __restrict__ l1b, const float* __restrict__ l2W,
                                              const float* __restrict__ l2b, float* __restrict__ out) {
    __shared__ float P[64 * 128];
    __shared__ float Z[64 * 64];
    int t = threadIdx.x;
    for (int i = t; i < 64 * 128; i += 256) {
        int g = i >> 7;
        float cnt = (float)max(gend[g] - gstart[g], 1);
        P[i] = pooled[i] / cnt;
    }
    __syncthreads();
    for (int o = t; o < 64 * 64; o += 256) {
        int g = o >> 6, j = o & 63;
        float s = l1b[j];
        for (int k = 0; k < 128; k++) s += P[g * 128 + k] * l1W[k * 64 + j];
        Z[o] = fmaxf(s, 0.f);
    }
    __syncthreads();
    if (t < 128) {
        int g = t >> 1, cls = t & 1;
        float s = l2b[cls];
        for (int k = 0; k < 64; k++) s += Z[g * 64 + k] * l2W[k * 2 + cls];
        out[g * 2 + cls] = s;
    }
}

extern "C" void kernel_launch(void* const* d_in, const int* in_sizes, int n_in, void* d_out, int out_size,
                              void* d_ws, size_t ws_size, hipStream_t stream) {
    (void)in_sizes; (void)n_in; (void)out_size; (void)ws_size;
    const float* x = (const float*)d_in[0];
    const int* ei = (const int*)d_in[1];
    const int* row = ei;
    const int* col = ei + NE;
    const int* batch = (const int*)d_in[2];
    const float* W1 = (const float*)d_in[3];
    const float* b1 = (const float*)d_in[4];
    const float* W2 = (const float*)d_in[5];
    const float* b2 = (const float*)d_in[6];
    const float* g1 = (const float*)d_in[7];
    const float* be1 = (const float*)d_in[8];
    const float* g2 = (const float*)d_in[9];
    const float* be2 = (const float*)d_in[10];
    const float* l1W = (const float*)d_in[11];
    const float* l1b = (const float*)d_in[12];
    const float* l2W = (const float*)d_in[13];
    const float* l2b = (const float*)d_in[14];
    float* out = (float*)d_out;

    char* ws = (char*)d_ws;
    size_t off = 0;
    auto alloc = [&](size_t bytes) {
        void* p = ws + off;
        off += (bytes + 255) & ~(size_t)255;
        return p;
    };
    unsigned int* g16 = (unsigned int*)alloc(NN * 64 * 4);   // packed fp16 (h*dinv)
    unsigned int* h16a = (unsigned int*)alloc(NN * 64 * 4);  // layer-1 agg out fp16
    unsigned int* h16b = (unsigned int*)alloc(NN * 64 * 4);  // layer-2 agg out fp16
    int* deg = (int*)alloc(NN * 4);
    float* dinv = (float*)alloc(NN * 4);
    int* indptr = (int*)alloc((NN + 1) * 4);
    int* cursor = (int*)alloc(NN * 4);
    int* esrc = (int*)alloc(NE * 4);
    int* partial = (int*)alloc(256 * 4);
    int* bsum = (int*)alloc(256 * 4);
    float* slabs = (float*)alloc(4 * 64 * 128 * 4);  // S1,Q1,S2,Q2
    float* ss1 = (float*)alloc(256 * 4);
    float* ss2 = (float*)alloc(256 * 4);
    float* pooled = (float*)alloc(NG * F * 4);
    int* gstart = (int*)alloc(NG * 4);
    int* gend = (int*)alloc(NG * 4);
    _Float16* wimg1 = (_Float16*)alloc(32768 * 2);
    _Float16* wimg2 = (_Float16*)alloc(32768 * 2);

    float* slab1S = slabs;
    float* slab1Q = slabs + 8192;
    float* slab2S = slabs + 16384;
    float* slab2Q = slabs + 24576;

    k_init<<<SCAN_NB, 256, 0, stream>>>(batch, deg, pooled, slabs, gstart, gend);
    k_wprep<<<128, 256, 0, stream>>>(W1, W2, wimg1, wimg2);
    k_deg<<<NE / 256, 256, 0, stream>>>(col, deg);
    k_scan1<<<SCAN_NB, 256, 0, stream>>>(deg, partial);
    k_scan2<<<1, 256, 0, stream>>>(partial, bsum, indptr);
    k_scan3<<<SCAN_NB, 256, 0, stream>>>(deg, bsum, indptr, cursor, dinv);
    k_fill<<<NE / 256, 256, 0, stream>>>(row, col, cursor, esrc);

    // layer 1
    k_mgemm<0><<<NN / 64, 256, 0, stream>>>(x, (const uint4*)wimg1, nullptr, dinv, (unsigned short*)g16);
    k_agg<<<NN / 4, 256, 0, stream>>>((const uint4*)g16, indptr, esrc, dinv, b1, (uint4*)h16a, slab1S, slab1Q);
    k_finalize<<<1, 128, 0, stream>>>(slab1S, slab1Q, g1, be1, ss1);

    // layer 2 (BN1+ReLU fused into GEMM A-load)
    k_mgemm<1><<<NN / 64, 256, 0, stream>>>(h16a, (const uint4*)wimg2, ss1, dinv, (unsigned short*)g16);
    k_agg<<<NN / 4, 256, 0, stream>>>((const uint4*)g16, indptr, esrc, dinv, b2, (uint4*)h16b, slab2S, slab2Q);
    k_finalize<<<1, 128, 0, stream>>>(slab2S, slab2Q, g2, be2, ss2);

    // pooling + head
    k_pool<<<NN / 64, 256, 0, stream>>>(h16b, batch, ss2, pooled);
    k_head<<<1, 256, 0, stream>>>(pooled, gstart, gend, l1W, l1b, l2W, l2b, out);
}